// Round 1
// baseline (176.478 us; speedup 1.0000x reference)
//
#include <hip/hip_runtime.h>
#include <math.h>

#define IMG_H 512
#define IMG_W 512
#define KW 11
#define RAD 5
#define TW 64
#define TH 32
#define LW (TW + 2 * RAD)   // 74
#define LH (TH + 2 * RAD)   // 42
#define LSTR 76             // padded LDS stride (floats)

#define C1F (0.01f * 0.01f)
#define C2F (0.03f * 0.03f)

__global__ __launch_bounds__(256, 2)
void ssim_fused_kernel(const float* __restrict__ A, const float* __restrict__ B,
                       float* __restrict__ out, float inv_total) {
    __shared__ float sA[LH][LSTR];
    __shared__ float sB[LH][LSTR];
    __shared__ float vA[TH][LSTR];
    __shared__ float vB[TH][LSTR];
    __shared__ float vP[TH][LSTR];
    __shared__ float wpart[4];

    const int tid = threadIdx.x;
    const int bx = blockIdx.x;   // 0..7  (x tiles)
    const int by = blockIdx.y;   // 0..15 (y tiles)
    const int img = blockIdx.z;  // 0..nimg-1

    // Gaussian weights (sigma=1.5, K=11), normalized — matches np fp32 to ~1 ulp.
    float w[KW];
    {
        float s = 0.f;
#pragma unroll
        for (int i = 0; i < KW; ++i) {
            float d = (float)(i - RAD);
            w[i] = expf(-(d * d) / 4.5f);
            s += w[i];
        }
        float inv = 1.0f / s;
#pragma unroll
        for (int i = 0; i < KW; ++i) w[i] *= inv;
    }

    const int x0 = bx * TW - RAD;
    const int y0 = by * TH - RAD;
    const float* __restrict__ Ai = A + (size_t)img * IMG_H * IMG_W;
    const float* __restrict__ Bi = B + (size_t)img * IMG_H * IMG_W;

    // ---- Stage A, B tiles (+halo) into LDS; zero-fill outside image ----
    for (int idx = tid; idx < LH * LW; idx += 256) {
        int r = idx / LW;
        int c = idx - r * LW;
        int gy = y0 + r;
        int gx = x0 + c;
        float a = 0.f, b = 0.f;
        if (gy >= 0 && gy < IMG_H && gx >= 0 && gx < IMG_W) {
            int g = gy * IMG_W + gx;
            a = Ai[g];
            b = Bi[g];
        }
        sA[r][c] = a;
        sB[r][c] = b;
    }
    __syncthreads();

    // ---- Vertical 1D conv: rows 0..TH-1, full halo width; P = A*B on the fly ----
    for (int idx = tid; idx < TH * LW; idx += 256) {
        int r = idx / LW;
        int c = idx - r * LW;
        float a = 0.f, b = 0.f, p = 0.f;
#pragma unroll
        for (int k = 0; k < KW; ++k) {
            float av = sA[r + k][c];
            float bv = sB[r + k][c];
            a += w[k] * av;
            b += w[k] * bv;
            p += w[k] * (av * bv);
        }
        vA[r][c] = a;
        vB[r][c] = b;
        vP[r][c] = p;
    }
    __syncthreads();

    // ---- Horizontal 1D conv + SSIM formula + per-thread accumulate ----
    float acc = 0.f;
    for (int idx = tid; idx < TH * TW; idx += 256) {  // exactly 8 iters
        int r = idx >> 6;
        int c = idx & 63;
        float mu1 = 0.f, mu2 = 0.f, sp = 0.f;
#pragma unroll
        for (int k = 0; k < KW; ++k) {
            mu1 += w[k] * vA[r][c + k];
            mu2 += w[k] * vB[r][c + k];
            sp  += w[k] * vP[r][c + k];
        }
        float m12 = mu1 * mu2;
        float sigma = sp - m12;
        float sq = mu1 * mu1 + mu2 * mu2;
        float num = (2.f * m12 + C1F) * (2.f * sigma + C2F);
        float den = (sq + C1F) * (sq + C2F);
        acc += num / den;
    }

    // ---- Reduce: wave shuffle -> LDS -> one atomic per block ----
#pragma unroll
    for (int off = 32; off > 0; off >>= 1)
        acc += __shfl_down(acc, off, 64);
    int wid = tid >> 6;
    int lane = tid & 63;
    if (lane == 0) wpart[wid] = acc;
    __syncthreads();
    if (tid == 0) {
        float s = (wpart[0] + wpart[1]) + (wpart[2] + wpart[3]);
        atomicAdd(out, s * inv_total);
    }
}

extern "C" void kernel_launch(void* const* d_in, const int* in_sizes, int n_in,
                              void* d_out, int out_size, void* d_ws, size_t ws_size,
                              hipStream_t stream) {
    const float* A = (const float*)d_in[0];
    const float* B = (const float*)d_in[1];
    float* out = (float*)d_out;

    const int total = in_sizes[0];                 // 32*1*512*512
    const int nimg = total / (IMG_H * IMG_W);      // 32

    // d_out is poisoned before every timed launch — zero it ourselves.
    hipMemsetAsync(d_out, 0, sizeof(float), stream);

    dim3 grid(IMG_W / TW, IMG_H / TH, nimg);       // (8, 16, 32)
    ssim_fused_kernel<<<grid, 256, 0, stream>>>(A, B, out, 1.0f / (float)total);
}

// Round 2
// 168.615 us; speedup vs baseline: 1.0466x; 1.0466x over previous
//
#include <hip/hip_runtime.h>
#include <math.h>

#define IMG_H 512
#define IMG_W 512
#define KW 11
#define RAD 5
#define TW 64          // output tile width
#define TH 32          // output tile height
#define VW 20          // float4 column-groups per row (80 floats: bx*64-8 .. +72)
#define VSTR 21        // LDS stride in float4 (84 floats; 84%32=20 -> no pow2 stride)

#define C1F (0.01f * 0.01f)
#define C2F (0.03f * 0.03f)

__global__ __launch_bounds__(256, 5)
void ssim_fused_kernel(const float* __restrict__ A, const float* __restrict__ B,
                       float* __restrict__ out, float inv_total) {
    // Vertical-conv intermediates only (no input staging): 3 * 32 * 21 * 16B = 32.25 KB
    // -> 5 blocks/CU (20 waves/CU) vs round-1's 2 blocks/CU.
    __shared__ float4 vA4[TH][VSTR];
    __shared__ float4 vB4[TH][VSTR];
    __shared__ float4 vP4[TH][VSTR];
    __shared__ float wpart[4];

    const int tid = threadIdx.x;
    const int bx = blockIdx.x;   // 0..7
    const int by = blockIdx.y;   // 0..15
    const int img = blockIdx.z;

    // Gaussian weights (sigma=1.5, K=11), normalized — matches np fp32 to ~1 ulp.
    float w[KW];
    {
        float s = 0.f;
#pragma unroll
        for (int i = 0; i < KW; ++i) {
            float d = (float)(i - RAD);
            w[i] = expf(-(d * d) / 4.5f);
            s += w[i];
        }
        float inv = 1.0f / s;
#pragma unroll
        for (int i = 0; i < KW; ++i) w[i] *= inv;
    }

    const float* __restrict__ Ai = A + (size_t)img * IMG_H * IMG_W;
    const float* __restrict__ Bi = B + (size_t)img * IMG_H * IMG_W;
    const int basex = bx * TW - 8;          // 16B-aligned frame start (covers -5..+68 halo)
    const int ybase = by * TH - RAD;

    // ---- Vertical 1D conv straight from global (float4, aligned), into LDS ----
    // Items: 32 rows x 20 vec-cols = 640; 256 threads -> 2.5 iters.
    for (int idx = tid; idx < TH * VW; idx += 256) {
        int r = idx / VW;
        int v = idx - r * VW;
        int colf = basex + 4 * v;           // whole-float4 in/out of image (512%4==0)
        float4 a = make_float4(0.f, 0.f, 0.f, 0.f);
        float4 b = a, p = a;
        if ((unsigned)colf < (unsigned)IMG_W) {
            int gy0 = ybase + r;
            const float* pa = Ai + (size_t)gy0 * IMG_W + colf;
            const float* pb = Bi + (size_t)gy0 * IMG_W + colf;
#pragma unroll
            for (int k = 0; k < KW; ++k) {
                int gy = gy0 + k;
                if ((unsigned)gy < (unsigned)IMG_H) {
                    float4 av = *(const float4*)(pa + (size_t)k * IMG_W);
                    float4 bv = *(const float4*)(pb + (size_t)k * IMG_W);
                    float wk = w[k];
                    a.x += wk * av.x; a.y += wk * av.y; a.z += wk * av.z; a.w += wk * av.w;
                    b.x += wk * bv.x; b.y += wk * bv.y; b.z += wk * bv.z; b.w += wk * bv.w;
                    p.x += wk * (av.x * bv.x); p.y += wk * (av.y * bv.y);
                    p.z += wk * (av.z * bv.z); p.w += wk * (av.w * bv.w);
                }
            }
        }
        vA4[r][v] = a;
        vB4[r][v] = b;
        vP4[r][v] = p;
    }
    __syncthreads();

    // ---- Horizontal 1D conv (b128 LDS reads) + SSIM formula ----
    // Items: 32 rows x 16 vec-outputs = 512; 2 iters/thread; 4 outputs/item.
    float acc = 0.f;
    for (int idx = tid; idx < TH * (TW / 4); idx += 256) {
        int r = idx >> 4;
        int j = idx & 15;                   // output cols co = 4j .. 4j+3
        // Window for outputs co..co+3: aligned cols (co+3)..(co+16) -> vecs j..j+4.
        float fa[20], fb[20], fp[20];
#pragma unroll
        for (int m = 0; m < 5; ++m) {
            float4 t = vA4[r][j + m];
            fa[4 * m] = t.x; fa[4 * m + 1] = t.y; fa[4 * m + 2] = t.z; fa[4 * m + 3] = t.w;
        }
#pragma unroll
        for (int m = 0; m < 5; ++m) {
            float4 t = vB4[r][j + m];
            fb[4 * m] = t.x; fb[4 * m + 1] = t.y; fb[4 * m + 2] = t.z; fb[4 * m + 3] = t.w;
        }
#pragma unroll
        for (int m = 0; m < 5; ++m) {
            float4 t = vP4[r][j + m];
            fp[4 * m] = t.x; fp[4 * m + 1] = t.y; fp[4 * m + 2] = t.z; fp[4 * m + 3] = t.w;
        }
#pragma unroll
        for (int o = 0; o < 4; ++o) {
            float mu1 = 0.f, mu2 = 0.f, sp = 0.f;
#pragma unroll
            for (int k = 0; k < KW; ++k) {
                mu1 += w[k] * fa[3 + o + k];
                mu2 += w[k] * fb[3 + o + k];
                sp  += w[k] * fp[3 + o + k];
            }
            float m12 = mu1 * mu2;
            float sigma = sp - m12;
            float sq = mu1 * mu1 + mu2 * mu2;
            float num = (2.f * m12 + C1F) * (2.f * sigma + C2F);
            float den = (sq + C1F) * (sq + C2F);
            acc += num / den;
        }
    }

    // ---- Reduce: wave shuffle -> LDS -> one atomic per block ----
#pragma unroll
    for (int off = 32; off > 0; off >>= 1)
        acc += __shfl_down(acc, off, 64);
    int wid = tid >> 6;
    int lane = tid & 63;
    if (lane == 0) wpart[wid] = acc;
    __syncthreads();
    if (tid == 0) {
        float s = (wpart[0] + wpart[1]) + (wpart[2] + wpart[3]);
        atomicAdd(out, s * inv_total);
    }
}

extern "C" void kernel_launch(void* const* d_in, const int* in_sizes, int n_in,
                              void* d_out, int out_size, void* d_ws, size_t ws_size,
                              hipStream_t stream) {
    const float* A = (const float*)d_in[0];
    const float* B = (const float*)d_in[1];
    float* out = (float*)d_out;

    const int total = in_sizes[0];                 // 32*1*512*512
    const int nimg = total / (IMG_H * IMG_W);      // 32

    hipMemsetAsync(d_out, 0, sizeof(float), stream);

    dim3 grid(IMG_W / TW, IMG_H / TH, nimg);       // (8, 16, 32)
    ssim_fused_kernel<<<grid, 256, 0, stream>>>(A, B, out, 1.0f / (float)total);
}

// Round 3
// 140.975 us; speedup vs baseline: 1.2518x; 1.1961x over previous
//
#include <hip/hip_runtime.h>
#include <math.h>

#define IMG_H 512
#define IMG_W 512
#define KW 11
#define RAD 5
#define T 8                 // output rows per thread
#define NG (IMG_W / 4)      // 128 float4 column-groups per row

#define C1F (0.01f * 0.01f)
#define C2F (0.03f * 0.03f)

__device__ __forceinline__ float ssim_px(float mu1, float mu2, float sp) {
    float m12 = mu1 * mu2;
    float sigma = sp - m12;
    float sq = mu1 * mu1 + mu2 * mu2;
    return ((2.f * m12 + C1F) * (2.f * sigma + C2F)) / ((sq + C1F) * (sq + C2F));
}

// Each thread: 4 cols (one float4 group) x 8 output rows, all in registers.
// Block: 256 threads = 128 col-groups x 2 row-chunks -> covers 512 wide x 16 rows.
// Grid: (32 row-blocks, 32 images).
__global__ __launch_bounds__(256, 2)
void ssim_fused_kernel(const float* __restrict__ A, const float* __restrict__ B,
                       float* __restrict__ out, float inv_total) {
    __shared__ float wpart[4];

    const int tid = threadIdx.x;
    const int g = tid & (NG - 1);        // col-group 0..127
    const int rchunk = tid >> 7;         // 0..1 (wave-uniform: waves 0,1 vs 2,3)
    const int img = blockIdx.y;
    const int ybase = blockIdx.x * (2 * T) + rchunk * T;   // first output row

    // Gaussian weights (sigma=1.5, K=11) — same fp32 recipe that matched np
    // bit-exactly in rounds 1-2. Forced into SGPRs (wave-uniform).
    float w[KW];
    {
        float s = 0.f;
#pragma unroll
        for (int i = 0; i < KW; ++i) {
            float d = (float)(i - RAD);
            w[i] = expf(-(d * d) / 4.5f);
            s += w[i];
        }
        float inv = 1.0f / s;
#pragma unroll
        for (int i = 0; i < KW; ++i) {
            w[i] *= inv;
            w[i] = __int_as_float(__builtin_amdgcn_readfirstlane(__float_as_int(w[i])));
        }
    }

    const float* __restrict__ Ai = A + (size_t)img * IMG_H * IMG_W;
    const float* __restrict__ Bi = B + (size_t)img * IMG_H * IMG_W;

    float4 accA[T], accB[T], accP[T];
#pragma unroll
    for (int o = 0; o < T; ++o) {
        accA[o] = make_float4(0.f, 0.f, 0.f, 0.f);
        accB[o] = accA[o];
        accP[o] = accA[o];
    }

    // Walk T + 2*RAD = 18 input rows; h-conv each, scatter into vertical accs.
#pragma unroll
    for (int i = 0; i < T + 2 * RAD; ++i) {
        int gy = ybase + i - RAD;
        if (gy >= 0 && gy < IMG_H) {     // wave-uniform branch (cheap s_cbranch)
            const float* rowA = Ai + (size_t)gy * IMG_W;
            const float* rowB = Bi + (size_t)gy * IMG_W;

            // Load 5 aligned float4 groups per array: cols 4g-8 .. 4g+11.
            float fa[20], fb[20];
#pragma unroll
            for (int m = 0; m < 5; ++m) {
                int gm = g + m - 2;
                float4 va = make_float4(0.f, 0.f, 0.f, 0.f);
                float4 vb = va;
                if ((unsigned)gm < (unsigned)NG) {   // only lanes 0,1,126,127 mask
                    va = *(const float4*)(rowA + 4 * gm);
                    vb = *(const float4*)(rowB + 4 * gm);
                }
                fa[4 * m] = va.x; fa[4 * m + 1] = va.y; fa[4 * m + 2] = va.z; fa[4 * m + 3] = va.w;
                fb[4 * m] = vb.x; fb[4 * m + 1] = vb.y; fb[4 * m + 2] = vb.z; fb[4 * m + 3] = vb.w;
            }

            // Horizontal 11-tap conv: output col j uses fa[3+j+k], k=0..10.
            float4 hA = make_float4(0.f, 0.f, 0.f, 0.f);
            float4 hB = hA, hP = hA;
#pragma unroll
            for (int k = 0; k < KW; ++k) {
                float wk = w[k];
                hA.x += wk * fa[3 + k];  hA.y += wk * fa[4 + k];
                hA.z += wk * fa[5 + k];  hA.w += wk * fa[6 + k];
                hB.x += wk * fb[3 + k];  hB.y += wk * fb[4 + k];
                hB.z += wk * fb[5 + k];  hB.w += wk * fb[6 + k];
                hP.x += wk * (fa[3 + k] * fb[3 + k]);
                hP.y += wk * (fa[4 + k] * fb[4 + k]);
                hP.z += wk * (fa[5 + k] * fb[5 + k]);
                hP.w += wk * (fa[6 + k] * fb[6 + k]);
            }

            // Vertical scatter: output o gets weight w[i-o] when 0 <= i-o <= 10.
#pragma unroll
            for (int o = 0; o < T; ++o) {
                if (i - o >= 0 && i - o < KW) {
                    float wk = w[i - o];
                    accA[o].x += wk * hA.x; accA[o].y += wk * hA.y;
                    accA[o].z += wk * hA.z; accA[o].w += wk * hA.w;
                    accB[o].x += wk * hB.x; accB[o].y += wk * hB.y;
                    accB[o].z += wk * hB.z; accB[o].w += wk * hB.w;
                    accP[o].x += wk * hP.x; accP[o].y += wk * hP.y;
                    accP[o].z += wk * hP.z; accP[o].w += wk * hP.w;
                }
            }
        }
    }

    // SSIM formula per pixel + per-thread accumulate (32 px/thread).
    float acc = 0.f;
#pragma unroll
    for (int o = 0; o < T; ++o) {
        acc += ssim_px(accA[o].x, accB[o].x, accP[o].x);
        acc += ssim_px(accA[o].y, accB[o].y, accP[o].y);
        acc += ssim_px(accA[o].z, accB[o].z, accP[o].z);
        acc += ssim_px(accA[o].w, accB[o].w, accP[o].w);
    }

    // Reduce: wave shuffle -> LDS -> one atomic per block.
#pragma unroll
    for (int off = 32; off > 0; off >>= 1)
        acc += __shfl_down(acc, off, 64);
    int wid = tid >> 6;
    int lane = tid & 63;
    if (lane == 0) wpart[wid] = acc;
    __syncthreads();
    if (tid == 0) {
        float s = (wpart[0] + wpart[1]) + (wpart[2] + wpart[3]);
        atomicAdd(out, s * inv_total);
    }
}

extern "C" void kernel_launch(void* const* d_in, const int* in_sizes, int n_in,
                              void* d_out, int out_size, void* d_ws, size_t ws_size,
                              hipStream_t stream) {
    const float* A = (const float*)d_in[0];
    const float* B = (const float*)d_in[1];
    float* out = (float*)d_out;

    const int total = in_sizes[0];                 // 32*1*512*512
    const int nimg = total / (IMG_H * IMG_W);      // 32

    hipMemsetAsync(d_out, 0, sizeof(float), stream);

    dim3 grid(IMG_H / (2 * T), nimg, 1);           // (32, 32)
    ssim_fused_kernel<<<grid, 256, 0, stream>>>(A, B, out, 1.0f / (float)total);
}